// Round 21
// baseline (70.427 us; speedup 1.0000x reference)
//
#include <hip/hip_runtime.h>

typedef __attribute__((ext_vector_type(8))) _Float16 half8;
typedef __attribute__((ext_vector_type(4))) _Float16 half4v;
typedef __attribute__((ext_vector_type(4))) float f32x4;
typedef float f32x4u __attribute__((ext_vector_type(4), aligned(4)));
typedef float f32x2u __attribute__((ext_vector_type(2), aligned(4)));

#define EPSF 1e-6f

__device__ __forceinline__ void glds16(const void* g, void* l) {
    __builtin_amdgcn_global_load_lds(
        (const __attribute__((address_space(1))) unsigned*)g,
        (__attribute__((address_space(3))) unsigned*)l, 16, 0, 0);
}
__device__ __forceinline__ unsigned short h2u(_Float16 h) {
    union { _Float16 h; unsigned short u; } c; c.h = h; return c.u;
}

// ---------------------------------------------------------------------------
// prep: Mh[f][768] = fp16 of stacked [A|Bw|Cw] (K-contig); Wh[g][256] = fp16(W).
// ---------------------------------------------------------------------------
__global__ __launch_bounds__(256) void prep_kernel(
    const float* __restrict__ A, const float* __restrict__ Bw,
    const float* __restrict__ Cw, const float* __restrict__ W,
    _Float16* __restrict__ Mh, _Float16* __restrict__ Wh)
{
    int f = blockIdx.x, e = threadIdx.x;
    Mh[f * 768 + e]       = (_Float16)A[f * 256 + e];
    Mh[f * 768 + 256 + e] = (_Float16)Bw[f * 256 + e];
    Mh[f * 768 + 512 + e] = (_Float16)Cw[f * 256 + e];
    Wh[f * 256 + e]       = (_Float16)W[f * 256 + e];
}

// ---------------------------------------------------------------------------
// fused v16: r15's FIFO-fence raw-barrier scheme at the (512,2) no-spill
// register contract.  Block 32n x 256f, 512 thr = 8 waves = 2 wc (48c) x
// 4 wf (64f) [r9 maps].  Per eb: [s_barrier] stage(eb+1)->A[nxt] (in flight
// across barriers); computeT(eb) (its vmcnt wait for xj(eb), issued AFTER
// stage(eb) last iter, transitively fences stage(eb) -- VMEM FIFO);
// [lgkmcnt(0); s_barrier]; loadXJ(eb+1); 3t x (4 af + 3 bf + 12 MFMA).
// No vmcnt(0) drains in the loop; sched_barrier(0) pins VMEM issue order.
// LDS: A 2x49152 @0 | T 23040 @98304 = 121344 -> 1 block/CU (8 waves).
// Trade vs r15: half occupancy, but VGPR cap 128 -> ~95 live, ZERO spill.
// part2: Y->LDS (96 x 512B swz) + GEMM2 + VN epilogue (r14/r19 512-thr,
// verified).  grid 512 (16 b x 32 n-tiles).
// ---------------------------------------------------------------------------
__global__ __launch_bounds__(512, 2)
void fused_kernel(
    const float* __restrict__ X, const float* __restrict__ Jp,
    const _Float16* __restrict__ Mh, const _Float16* __restrict__ Wh,
    float* __restrict__ out)
{
    extern __shared__ char lds[];
    const int T_BASE = 98304;
    int tid = threadIdx.x;
    int b  = blockIdx.x >> 5;
    int n0 = (blockIdx.x & 31) * 32;

    int l = tid & 63, lr = l & 15, lq = l >> 4;
    int w = tid >> 6;                 // 0..7
    int wc = w & 1, wf = w >> 1;      // wc: c-half (48c), wf: f-quarter (64f)
    int nl = tid >> 4, ep = tid & 15; // computeT: row nl (0..31), 2 pts e=2ep

    // stage 3 t-slices of M[., eb*32..+32] (48 KB) into A[p]; 6 glds16/thread
    auto stageEB = [&](int p, int eb) {
        #pragma unroll
        for (int h = 0; h < 6; ++h) {
            int m = h * 512 + tid;                  // 0..3071
            int t = m >> 10, fr = (m >> 2) & 255, slot = m & 3;
            size_t go = ((size_t)fr * 768 + t * 256 + eb * 32
                         + ((slot ^ ((fr >> 1) & 3)) * 8)) * 2;
            glds16((const char*)Mh + go, lds + p * 49152 + m * 16);
        }
    };

    size_t pb0 = ((size_t)((b * 1024 + n0 + nl) * 256) + 2 * ep) * 3;
    auto loadXJ = [&](int eb, float* xs, float* js) {
        size_t pb = pb0 + (size_t)eb * 96;
        f32x4u xa = *(const f32x4u*)(X + pb);
        f32x2u xb = *(const f32x2u*)(X + pb + 4);
        f32x4u ja = *(const f32x4u*)(Jp + pb);
        f32x2u jb = *(const f32x2u*)(Jp + pb + 4);
        xs[0]=xa[0]; xs[1]=xa[1]; xs[2]=xa[2]; xs[3]=xa[3]; xs[4]=xb[0]; xs[5]=xb[1];
        js[0]=ja[0]; js[1]=ja[1]; js[2]=ja[2]; js[3]=ja[3]; js[4]=jb[0]; js[5]=jb[1];
    };

    auto computeT = [&](const float* xs, const float* js) {
        unsigned short hv[2][9];
        #pragma unroll
        for (int p = 0; p < 2; ++p) {
            float x0 = xs[3*p], x1 = xs[3*p+1], x2 = xs[3*p+2];
            float j0 = js[3*p], j1 = js[3*p+1], j2 = js[3*p+2];
            float jj  = j0*j0 + j1*j1 + j2*j2;
            float rn  = __builtin_amdgcn_rcpf(__builtin_amdgcn_sqrtf(jj) + EPSF);
            float nj0 = j0*rn, nj1 = j1*rn, nj2 = j2*rn;
            float s2  = nj0*nj0 + nj1*nj1;
            float uz  = -s2 * __builtin_amdgcn_rcpf(nj2 + EPSF);
            float ru  = __builtin_amdgcn_rcpf(__builtin_amdgcn_sqrtf(s2 + uz*uz) + EPSF);
            float u0 = nj0*ru, u1 = nj1*ru, u2 = uz*ru;
            float v0 = u1*nj2 - u2*nj1;
            float v1 = u2*nj0 - u0*nj2;
            float v2 = u0*nj1 - u1*nj0;
            float r0 = u0*x0 + v0*x1 + nj0*x2;
            float r1 = u1*x0 + v1*x1 + nj1*x2;
            float r2 = u2*x0 + v2*x1 + nj2*x2;
            hv[p][0] = h2u((_Float16)(u0*r0 + u1*r1));
            hv[p][1] = h2u((_Float16)(v0*r0 + v1*r1));
            hv[p][2] = h2u((_Float16)(nj0*r0 + nj1*r1));
            hv[p][3] = h2u((_Float16)(u1*r0 - u0*r1));
            hv[p][4] = h2u((_Float16)(v1*r0 - v0*r1));
            hv[p][5] = h2u((_Float16)(nj1*r0 - nj0*r1));
            hv[p][6] = h2u((_Float16)(u2*r2));
            hv[p][7] = h2u((_Float16)(v2*r2));
            hv[p][8] = h2u((_Float16)(nj2*r2));
        }
        #pragma unroll
        for (int s = 0; s < 9; ++s) {
            int t = s / 3, i = s % 3;
            unsigned pk = (unsigned)hv[0][s] | ((unsigned)hv[1][s] << 16);
            *(unsigned*)(lds + T_BASE + (t * 96 + i * 32 + nl) * 80 + ep * 4) = pk;
        }
    };

    f32x4 acc[3][4] = {};
    float xs[6], js[6];

    // prologue: A[0] staged, then XJ(0) (xj younger than stage -> FIFO fence)
    stageEB(0, 0);
    __builtin_amdgcn_sched_barrier(0);
    loadXJ(0, xs, js);
    __builtin_amdgcn_sched_barrier(0);

    for (int eb = 0; eb < 8; ++eb) {
        int cur = eb & 1;
        __builtin_amdgcn_s_barrier();               // B1 raw: T safe to rewrite
        if (eb < 7) {
            stageEB(cur ^ 1, eb + 1);               // stays in flight across barriers
            __builtin_amdgcn_sched_barrier(0);
        }
        computeT(xs, js);    // vmcnt wait for xj(eb) fences stage(eb) (FIFO)
        asm volatile("s_waitcnt lgkmcnt(0)" ::: "memory");
        __builtin_amdgcn_sched_barrier(0);
        __builtin_amdgcn_s_barrier();               // B2 raw: T visible
        __builtin_amdgcn_sched_barrier(0);
        if (eb < 7) {
            loadXJ(eb + 1, xs, js);                 // consumed next iter (fence)
            __builtin_amdgcn_sched_barrier(0);
        }

        #pragma unroll
        for (int t = 0; t < 3; ++t) {
            half8 af[4], bf[3];
            #pragma unroll
            for (int mi = 0; mi < 4; ++mi) {
                int f = wf * 64 + mi * 16 + lr;
                af[mi] = *(const half8*)(lds + cur * 49152 + t * 16384 + f * 64
                                         + ((lq ^ ((f >> 1) & 3)) * 16));
            }
            #pragma unroll
            for (int bi = 0; bi < 3; ++bi) {
                int cr = wc * 48 + bi * 16 + lr;
                bf[bi] = *(const half8*)(lds + T_BASE + (t * 96 + cr) * 80 + lq * 16);
            }
            #pragma unroll
            for (int bi = 0; bi < 3; ++bi)
                #pragma unroll
                for (int mi = 0; mi < 4; ++mi)
                    acc[bi][mi] = __builtin_amdgcn_mfma_f32_16x16x32_f16(
                        af[mi], bf[bi], acc[bi][mi], 0, 0, 0);
        }
    }

    // ---------------- part 2: Y -> LDS, GEMM2 + VN epilogue (r14/r19) -----
    __builtin_amdgcn_s_barrier();       // all part1 LDS reads consumed
    // Y tile: 96 rows (c = i*32 + n_loc) x 512 B, byte ^= (c&7)<<4
    #pragma unroll
    for (int bi = 0; bi < 3; ++bi) {
        int c = wc * 48 + bi * 16 + lr;
        #pragma unroll
        for (int mi = 0; mi < 4; ++mi) {
            int fb2 = (wf * 64 + mi * 16 + lq * 4) * 2;
            f32x4 v = acc[bi][mi];
            half4v p;
            p.x = (_Float16)v[0]; p.y = (_Float16)v[1];
            p.z = (_Float16)v[2]; p.w = (_Float16)v[3];
            *(half4v*)(lds + c * 512 + (fb2 ^ ((c & 7) << 4))) = p;
        }
    }

    int nh = w & 1, gw = w >> 1;   // re-tile: 2 n-halves (16) x 4 g-quarters (64)
    half8 wreg[2][4];
    #pragma unroll
    for (int gf = 0; gf < 4; ++gf) {
        int g = gw * 64 + gf * 16 + lr;
        wreg[0][gf] = *(const half8*)(Wh + (size_t)g * 256 + lq * 8);
    }
    __syncthreads();               // Y_lds visible (single full drain, OK)

    f32x4 acc2[3][4] = {};
    #pragma unroll
    for (int kt = 0; kt < 8; ++kt) {
        if (kt < 7) {
            #pragma unroll
            for (int gf = 0; gf < 4; ++gf) {
                int g = gw * 64 + gf * 16 + lr;
                wreg[(kt + 1) & 1][gf] =
                    *(const half8*)(Wh + (size_t)g * 256 + (kt + 1) * 32 + lq * 8);
            }
        }
        half8 yf[3];
        #pragma unroll
        for (int ci = 0; ci < 3; ++ci) {
            int c = ci * 32 + nh * 16 + lr;
            yf[ci] = *(const half8*)(lds + c * 512
                                     + ((kt * 64 + lq * 16) ^ ((c & 7) << 4)));
        }
        #pragma unroll
        for (int ci = 0; ci < 3; ++ci)
            #pragma unroll
            for (int gf = 0; gf < 4; ++gf)
                acc2[ci][gf] = __builtin_amdgcn_mfma_f32_16x16x32_f16(
                    yf[ci], wreg[kt & 1][gf], acc2[ci][gf], 0, 0, 0);
    }

    // epilogue: lane holds d_i for (g = gw*64+gf*16+lr, n = nh*16+lq*4+r)
    #pragma unroll
    for (int gf = 0; gf < 4; ++gf) {
        int g = gw * 64 + gf * 16 + lr;
        f32x4 o[3];
        #pragma unroll
        for (int r = 0; r < 4; ++r) {
            float xv[3];
            #pragma unroll
            for (int ci = 0; ci < 3; ++ci) {
                int c = ci * 32 + nh * 16 + lq * 4 + r;
                xv[ci] = (float)*(const _Float16*)(lds + c * 512
                                 + ((g * 2) ^ ((c & 7) << 4)));
            }
            float d0 = acc2[0][gf][r], d1 = acc2[1][gf][r], d2 = acc2[2][gf][r];
            float dot = xv[0] * d0 + xv[1] * d1 + xv[2] * d2;
            float dn  = d0 * d0 + d1 * d1 + d2 * d2;
            float sc  = dot / (dn + EPSF);
            bool pos  = dot >= 0.0f;
            float l0 = pos ? xv[0] : fmaf(-sc, d0, xv[0]);
            float l1 = pos ? xv[1] : fmaf(-sc, d1, xv[1]);
            float l2 = pos ? xv[2] : fmaf(-sc, d2, xv[2]);
            o[0][r] = fmaf(0.8f, l0, 0.2f * xv[0]);
            o[1][r] = fmaf(0.8f, l1, 0.2f * xv[1]);
            o[2][r] = fmaf(0.8f, l2, 0.2f * xv[2]);
        }
        int nb = n0 + nh * 16 + lq * 4;
        #pragma unroll
        for (int i = 0; i < 3; ++i)
            *(f32x4*)(out + ((size_t)(b * 256 + g) * 3 + i) * 1024 + nb) = o[i];
    }
}

extern "C" void kernel_launch(void* const* d_in, const int* in_sizes, int n_in,
                              void* d_out, int out_size, void* d_ws, size_t ws_size,
                              hipStream_t stream)
{
    const float* X  = (const float*)d_in[0];
    const float* J  = (const float*)d_in[1];
    const float* A  = (const float*)d_in[2];
    const float* Bw = (const float*)d_in[3];
    const float* Cw = (const float*)d_in[4];
    const float* W  = (const float*)d_in[5];
    float* out = (float*)d_out;

    char* ws = (char*)d_ws;
    _Float16* Mh = (_Float16*)ws;                       // 256*768*2 = 393216
    _Float16* Wh = (_Float16*)(ws + 393216);            // 256*256*2 = 131072

    (void)hipFuncSetAttribute((const void*)fused_kernel,
                              hipFuncAttributeMaxDynamicSharedMemorySize, 121344);

    hipLaunchKernelGGL(prep_kernel,  dim3(256), dim3(256), 0, stream,
                       A, Bw, Cw, W, Mh, Wh);
    hipLaunchKernelGGL(fused_kernel, dim3(512), dim3(512), 121344, stream,
                       X, J, Mh, Wh, out);
}

// Round 22
// 54.448 us; speedup vs baseline: 1.2935x; 1.2935x over previous
//
#include <hip/hip_runtime.h>

typedef __attribute__((ext_vector_type(8))) _Float16 half8;
typedef __attribute__((ext_vector_type(4))) _Float16 half4v;
typedef __attribute__((ext_vector_type(4))) float f32x4;
typedef float f32x4u __attribute__((ext_vector_type(4), aligned(4)));
typedef float f32x2u __attribute__((ext_vector_type(2), aligned(4)));

#define EPSF 1e-6f

__device__ __forceinline__ void glds16(const void* g, void* l) {
    __builtin_amdgcn_global_load_lds(
        (const __attribute__((address_space(1))) unsigned*)g,
        (__attribute__((address_space(3))) unsigned*)l, 16, 0, 0);
}
__device__ __forceinline__ unsigned short h2u(_Float16 h) {
    union { _Float16 h; unsigned short u; } c; c.h = h; return c.u;
}

// ---------------------------------------------------------------------------
// prep: Mh[f][768] = fp16 of stacked [A|Bw|Cw] (K-contig); Wh[g][256] = fp16(W).
// ---------------------------------------------------------------------------
__global__ __launch_bounds__(256) void prep_kernel(
    const float* __restrict__ A, const float* __restrict__ Bw,
    const float* __restrict__ Cw, const float* __restrict__ W,
    _Float16* __restrict__ Mh, _Float16* __restrict__ Wh)
{
    int f = blockIdx.x, e = threadIdx.x;
    Mh[f * 768 + e]       = (_Float16)A[f * 256 + e];
    Mh[f * 768 + 256 + e] = (_Float16)Bw[f * 256 + e];
    Mh[f * 768 + 512 + e] = (_Float16)Cw[f * 256 + e];
    Wh[f * 256 + e]       = (_Float16)W[f * 256 + e];
}

// ---------------------------------------------------------------------------
// fused v11 (FINAL, best measured 54.8 us; reproduced 54.9): raw-barrier
// pipelined staging.  Block 64n x 256f, 1024 thr = 16 waves = 4 wc (48c) x
// 4 wf (64f).  Per eb: [s_barrier] stage(eb+1)->A[nxt] (async, stays in
// flight across barriers); computeT(eb)->T (its compiler-inserted vmcnt wait
// for xj(eb) transitively fences stage(eb): xj(eb) was issued AFTER it ->
// VMEM FIFO); [lgkmcnt(0); s_barrier]; loadXJ(eb+1); 3t x (4af+3bf+12 MFMA).
// NO vmcnt(0) drains in the loop.  sched_barrier(0) pins VMEM issue order.
// LDS: A 2x49152 @0 | T 46080 @98304 = 144384 -> 1 block/CU; grid 256 = 1/CU.
// Known residuals (measured, not fixable at positive EV in this harness):
// ~6 MB spill traffic (allocator locks 1024-thr blocks at 64 VGPR; the
// no-spill 512-thr variant = 70.4 us — occupancy beats spill), af 4-way bank
// conflict (64-B A-rows, glds16 needs contiguous dest so no pad), and the
// 2-phase serialization floor (counted-vmcnt variant raced; m152).
// part2: Y->LDS (192 x 512B swz) + GEMM2 + VN epilogue.
// ---------------------------------------------------------------------------
__global__ __launch_bounds__(1024, 2)
void fused_kernel(
    const float* __restrict__ X, const float* __restrict__ Jp,
    const _Float16* __restrict__ Mh, const _Float16* __restrict__ Wh,
    float* __restrict__ out)
{
    extern __shared__ char lds[];
    const int T_BASE = 98304;
    int tid = threadIdx.x;
    int b  = blockIdx.x >> 4;
    int n0 = (blockIdx.x & 15) * 64;

    int l = tid & 63, lr = l & 15, lq = l >> 4;
    int w = tid >> 6;                 // 0..15
    int wf = w & 3, wc = w >> 2;      // part1: wf f-quarter (64f), wc c-quarter (48c)
    int nl = tid >> 4, ep = tid & 15; // computeT: row nl (0..63), 2 pts at e=2*ep

    // stage 3 t-slices of M[., eb*32..+32] (48 KB) into A[p]; 3 glds16/thread
    auto stageEB = [&](int p, int eb) {
        #pragma unroll
        for (int h = 0; h < 3; ++h) {
            int m = h * 1024 + tid;                 // 0..3071
            int t = m >> 10, fr = (m >> 2) & 255, slot = m & 3;
            size_t go = ((size_t)fr * 768 + t * 256 + eb * 32
                         + ((slot ^ ((fr >> 1) & 3)) * 8)) * 2;
            glds16((const char*)Mh + go, lds + p * 49152 + m * 16);
        }
    };

    size_t pb0 = ((size_t)((b * 1024 + n0 + nl) * 256) + 2 * ep) * 3;
    auto loadXJ = [&](int eb, float* xs, float* js) {
        size_t pb = pb0 + (size_t)eb * 96;
        f32x4u xa = *(const f32x4u*)(X + pb);
        f32x2u xb = *(const f32x2u*)(X + pb + 4);
        f32x4u ja = *(const f32x4u*)(Jp + pb);
        f32x2u jb = *(const f32x2u*)(Jp + pb + 4);
        xs[0]=xa[0]; xs[1]=xa[1]; xs[2]=xa[2]; xs[3]=xa[3]; xs[4]=xb[0]; xs[5]=xb[1];
        js[0]=ja[0]; js[1]=ja[1]; js[2]=ja[2]; js[3]=ja[3]; js[4]=jb[0]; js[5]=jb[1];
    };

    auto computeT = [&](const float* xs, const float* js) {
        unsigned short hv[2][9];
        #pragma unroll
        for (int p = 0; p < 2; ++p) {
            float x0 = xs[3*p], x1 = xs[3*p+1], x2 = xs[3*p+2];
            float j0 = js[3*p], j1 = js[3*p+1], j2 = js[3*p+2];
            float jj  = j0*j0 + j1*j1 + j2*j2;
            float rn  = __builtin_amdgcn_rcpf(__builtin_amdgcn_sqrtf(jj) + EPSF);
            float nj0 = j0*rn, nj1 = j1*rn, nj2 = j2*rn;
            float s2  = nj0*nj0 + nj1*nj1;
            float uz  = -s2 * __builtin_amdgcn_rcpf(nj2 + EPSF);
            float ru  = __builtin_amdgcn_rcpf(__builtin_amdgcn_sqrtf(s2 + uz*uz) + EPSF);
            float u0 = nj0*ru, u1 = nj1*ru, u2 = uz*ru;
            float v0 = u1*nj2 - u2*nj1;
            float v1 = u2*nj0 - u0*nj2;
            float v2 = u0*nj1 - u1*nj0;
            float r0 = u0*x0 + v0*x1 + nj0*x2;
            float r1 = u1*x0 + v1*x1 + nj1*x2;
            float r2 = u2*x0 + v2*x1 + nj2*x2;
            hv[p][0] = h2u((_Float16)(u0*r0 + u1*r1));
            hv[p][1] = h2u((_Float16)(v0*r0 + v1*r1));
            hv[p][2] = h2u((_Float16)(nj0*r0 + nj1*r1));
            hv[p][3] = h2u((_Float16)(u1*r0 - u0*r1));
            hv[p][4] = h2u((_Float16)(v1*r0 - v0*r1));
            hv[p][5] = h2u((_Float16)(nj1*r0 - nj0*r1));
            hv[p][6] = h2u((_Float16)(u2*r2));
            hv[p][7] = h2u((_Float16)(v2*r2));
            hv[p][8] = h2u((_Float16)(nj2*r2));
        }
        #pragma unroll
        for (int s = 0; s < 9; ++s) {
            int t = s / 3, i = s % 3;
            unsigned pk = (unsigned)hv[0][s] | ((unsigned)hv[1][s] << 16);
            *(unsigned*)(lds + T_BASE + (t * 192 + i * 64 + nl) * 80 + ep * 4) = pk;
        }
    };

    f32x4 acc[3][4] = {};
    float xs[6], js[6];

    // prologue: A[0] staged, then XJ(0) (xj younger than stage -> FIFO fence)
    stageEB(0, 0);
    __builtin_amdgcn_sched_barrier(0);
    loadXJ(0, xs, js);
    __builtin_amdgcn_sched_barrier(0);

    for (int eb = 0; eb < 8; ++eb) {
        int cur = eb & 1;
        __builtin_amdgcn_s_barrier();               // B1 raw: T safe to rewrite
        if (eb < 7) {
            stageEB(cur ^ 1, eb + 1);               // stays in flight across barriers
            __builtin_amdgcn_sched_barrier(0);
        }
        computeT(xs, js);    // vmcnt wait for xj(eb) fences stage(eb) (FIFO)
        asm volatile("s_waitcnt lgkmcnt(0)" ::: "memory");
        __builtin_amdgcn_sched_barrier(0);
        __builtin_amdgcn_s_barrier();               // B2 raw: T visible
        __builtin_amdgcn_sched_barrier(0);
        if (eb < 7) {
            loadXJ(eb + 1, xs, js);                 // consumed next iter (fence)
            __builtin_amdgcn_sched_barrier(0);
        }

        #pragma unroll
        for (int t = 0; t < 3; ++t) {
            half8 af[4], bf[3];
            #pragma unroll
            for (int mi = 0; mi < 4; ++mi) {
                int f = wf * 64 + mi * 16 + lr;
                af[mi] = *(const half8*)(lds + cur * 49152 + t * 16384 + f * 64
                                         + ((lq ^ ((f >> 1) & 3)) * 16));
            }
            #pragma unroll
            for (int bi = 0; bi < 3; ++bi) {
                int cr = wc * 48 + bi * 16 + lr;
                bf[bi] = *(const half8*)(lds + T_BASE + (t * 192 + cr) * 80 + lq * 16);
            }
            #pragma unroll
            for (int bi = 0; bi < 3; ++bi)
                #pragma unroll
                for (int mi = 0; mi < 4; ++mi)
                    acc[bi][mi] = __builtin_amdgcn_mfma_f32_16x16x32_f16(
                        af[mi], bf[bi], acc[bi][mi], 0, 0, 0);
        }
    }

    // ---------------- part 2: Y -> LDS, GEMM2 + VN epilogue ----------------
    __builtin_amdgcn_s_barrier();       // all part1 LDS reads consumed
    // Y tile: 192 rows (c = i*64 + n_loc = flat c), 512-B pitch, ^(c&7)<<4
    #pragma unroll
    for (int bi = 0; bi < 3; ++bi) {
        int c = wc * 48 + bi * 16 + lr;
        #pragma unroll
        for (int mi = 0; mi < 4; ++mi) {
            int fb2 = (wf * 64 + mi * 16 + lq * 4) * 2;
            f32x4 v = acc[bi][mi];
            half4v p;
            p.x = (_Float16)v[0]; p.y = (_Float16)v[1];
            p.z = (_Float16)v[2]; p.w = (_Float16)v[3];
            *(half4v*)(lds + c * 512 + (fb2 ^ ((c & 7) << 4))) = p;
        }
    }

    int nh = w & 1, gw = w >> 1;   // re-tile: 2 n-halves (32) x 8 g-eighths (32)
    half8 wreg[2][2];
    #pragma unroll
    for (int gf = 0; gf < 2; ++gf) {
        int g = gw * 32 + gf * 16 + lr;
        wreg[0][gf] = *(const half8*)(Wh + (size_t)g * 256 + lq * 8);
    }
    asm volatile("s_waitcnt lgkmcnt(0)" ::: "memory");
    __builtin_amdgcn_sched_barrier(0);
    __builtin_amdgcn_s_barrier();       // Y_lds visible
    __builtin_amdgcn_sched_barrier(0);

    f32x4 acc2[3][2][2] = {};
    #pragma unroll
    for (int kt = 0; kt < 8; ++kt) {
        if (kt < 7) {
            #pragma unroll
            for (int gf = 0; gf < 2; ++gf) {
                int g = gw * 32 + gf * 16 + lr;
                wreg[(kt + 1) & 1][gf] =
                    *(const half8*)(Wh + (size_t)g * 256 + (kt + 1) * 32 + lq * 8);
            }
        }
        #pragma unroll
        for (int ci = 0; ci < 3; ++ci)
            #pragma unroll
            for (int nc = 0; nc < 2; ++nc) {
                int c = ci * 64 + nh * 32 + nc * 16 + lr;
                half8 yf = *(const half8*)(lds + c * 512
                             + ((kt * 64 + lq * 16) ^ ((c & 7) << 4)));
                #pragma unroll
                for (int gf = 0; gf < 2; ++gf)
                    acc2[ci][nc][gf] = __builtin_amdgcn_mfma_f32_16x16x32_f16(
                        yf, wreg[kt & 1][gf], acc2[ci][nc][gf], 0, 0, 0);
            }
    }

    // epilogue: lane holds d_i for (g = gw*32+gf*16+lr, n = nh*32+nc*16+lq*4+r)
    #pragma unroll
    for (int nc = 0; nc < 2; ++nc)
        #pragma unroll
        for (int gf = 0; gf < 2; ++gf) {
            int g = gw * 32 + gf * 16 + lr;
            f32x4 o[3];
            #pragma unroll
            for (int r = 0; r < 4; ++r) {
                float xv[3];
                #pragma unroll
                for (int ci = 0; ci < 3; ++ci) {
                    int c = ci * 64 + nh * 32 + nc * 16 + lq * 4 + r;
                    xv[ci] = (float)*(const _Float16*)(lds + c * 512
                                     + ((g * 2) ^ ((c & 7) << 4)));
                }
                float d0 = acc2[0][nc][gf][r], d1 = acc2[1][nc][gf][r], d2 = acc2[2][nc][gf][r];
                float dot = xv[0] * d0 + xv[1] * d1 + xv[2] * d2;
                float dn  = d0 * d0 + d1 * d1 + d2 * d2;
                float sc  = dot / (dn + EPSF);
                bool pos  = dot >= 0.0f;
                float l0 = pos ? xv[0] : fmaf(-sc, d0, xv[0]);
                float l1 = pos ? xv[1] : fmaf(-sc, d1, xv[1]);
                float l2 = pos ? xv[2] : fmaf(-sc, d2, xv[2]);
                o[0][r] = fmaf(0.8f, l0, 0.2f * xv[0]);
                o[1][r] = fmaf(0.8f, l1, 0.2f * xv[1]);
                o[2][r] = fmaf(0.8f, l2, 0.2f * xv[2]);
            }
            int nb = n0 + nh * 32 + nc * 16 + lq * 4;
            #pragma unroll
            for (int i = 0; i < 3; ++i)
                *(f32x4*)(out + ((size_t)(b * 256 + g) * 3 + i) * 1024 + nb) = o[i];
        }
}

extern "C" void kernel_launch(void* const* d_in, const int* in_sizes, int n_in,
                              void* d_out, int out_size, void* d_ws, size_t ws_size,
                              hipStream_t stream)
{
    const float* X  = (const float*)d_in[0];
    const float* J  = (const float*)d_in[1];
    const float* A  = (const float*)d_in[2];
    const float* Bw = (const float*)d_in[3];
    const float* Cw = (const float*)d_in[4];
    const float* W  = (const float*)d_in[5];
    float* out = (float*)d_out;

    char* ws = (char*)d_ws;
    _Float16* Mh = (_Float16*)ws;                       // 256*768*2 = 393216
    _Float16* Wh = (_Float16*)(ws + 393216);            // 256*256*2 = 131072

    (void)hipFuncSetAttribute((const void*)fused_kernel,
                              hipFuncAttributeMaxDynamicSharedMemorySize, 144384);

    hipLaunchKernelGGL(prep_kernel,  dim3(256), dim3(256),  0, stream,
                       A, Bw, Cw, W, Mh, Wh);
    hipLaunchKernelGGL(fused_kernel, dim3(256), dim3(1024), 144384, stream,
                       X, J, Mh, Wh, out);
}